// Round 1
// 1447.734 us; speedup vs baseline: 1.0195x; 1.0195x over previous
//
#include <hip/hip_runtime.h>

typedef __attribute__((ext_vector_type(8))) short short8;   // 8 bf16 = 4 VGPRs (MFMA A/B frag)
typedef __attribute__((ext_vector_type(4))) float floatx4;  // MFMA C/D frag
typedef __attribute__((ext_vector_type(4))) unsigned short ushort4v;

// split fp32 v ~= hi + lo (both bf16). hi = RN(v), lo = trunc(v - hi). rel err ~2^-17.
__device__ inline void split_bf16(float v, unsigned short &h, unsigned short &l) {
    unsigned u = __float_as_uint(v);
    unsigned hu = (u + 0x8000u) & 0xFFFF0000u;
    h = (unsigned short)(hu >> 16);
    float lf = v - __uint_as_float(hu);
    l = (unsigned short)(__float_as_uint(lf) >> 16);
}

// ===== Prep combined encoder weight: W_enc[64 cols][1536 k] hi/lo, B-frag order [col][k] =====
// col<28: des weight (k<768), zero for k>=768. col>=28: tweet weight (k>=768), zero below.
__global__ void prep_wenc_kernel(const float* __restrict__ Wd, const float* __restrict__ Wt,
                                 unsigned short* __restrict__ dh, unsigned short* __restrict__ dl)
{
    int col = blockIdx.x;                       // 0..63
    int k   = blockIdx.y * 256 + threadIdx.x;   // 0..1535
    float v;
    if (col < 28) v = (k < 768)  ? Wd[(size_t)k * 28 + col] : 0.f;
    else          v = (k >= 768) ? Wt[(size_t)(k - 768) * 36 + (col - 28)] : 0.f;
    unsigned short h, l;
    split_bf16(v, h, l);
    dh[(size_t)col * 1536 + k] = h;
    dl[(size_t)col * 1536 + k] = l;
}

// ===== Encoder big via MFMA: x[:,0:64] = lrelu([des|tweet] @ blockdiag(Wd,Wt) + [bd|bt]) =====
// 64 rows/block, 256 thr = 4 waves; wave w owns col-tile w (cols w*16..w*16+15).
// K=1536 staged in 12 phases of 128: phases 0..5 from des, 6..11 from tweet.
// fp32 accuracy via bf16 hi/lo 3-mult (same scheme as dense_mfma_kernel).
__global__ __launch_bounds__(256, 4) void enc_mfma_kernel(
    const float* __restrict__ des, const float* __restrict__ tweet,
    const unsigned short* __restrict__ Wh, const unsigned short* __restrict__ Wl,
    const float* __restrict__ bd, const float* __restrict__ bt,
    float* __restrict__ out, int N)
{
    __shared__ unsigned short Xh[64][136];   // 17 KB (row stride 272B: 16B-aligned frags)
    __shared__ unsigned short Xl[64][136];   // 17 KB
    int base = blockIdx.x * 64;
    int lane = threadIdx.x & 63;
    int wv   = threadIdx.x >> 6;
    int srow = threadIdx.x >> 2;      // staging: row 0..63
    int sseg = threadIdx.x & 3;       // staging: 32-float segment
    int mrow = lane & 15;             // A row / B col / D col within tile
    int quad = lane >> 4;

    floatx4 acc[4];
#pragma unroll
    for (int t = 0; t < 4; t++) acc[t] = (floatx4){0.f, 0.f, 0.f, 0.f};

    for (int p = 0; p < 12; p++) {
        const float* inp = (p < 6) ? des : tweet;
        int k0 = (p < 6) ? p * 128 : (p - 6) * 128;

        __syncthreads();   // prior phase's frag reads done before restaging
        {
            int gr = base + srow; if (gr >= N) gr = N - 1;
            const float* src = inp + (size_t)gr * 768 + k0 + sseg * 32;
#pragma unroll
            for (int q = 0; q < 8; q++) {
                float4 v = *(const float4*)(src + q * 4);
                unsigned short h0, h1, h2, h3, l0, l1, l2, l3;
                split_bf16(v.x, h0, l0);
                split_bf16(v.y, h1, l1);
                split_bf16(v.z, h2, l2);
                split_bf16(v.w, h3, l3);
                ushort4v hv = {h0, h1, h2, h3};
                ushort4v lv = {l0, l1, l2, l3};
                *(ushort4v*)&Xh[srow][sseg * 32 + q * 4] = hv;
                *(ushort4v*)&Xl[srow][sseg * 32 + q * 4] = lv;
            }
        }
        __syncthreads();

        // block-diagonal zero-skip: wave0 (cols 0..15) des-only; waves 2,3 tweet-only
        bool active = (wv == 1) || ((wv == 0) ? (p < 6) : (p >= 6));
        if (active) {
            const unsigned short* wh = Wh + (size_t)(wv * 16 + mrow) * 1536 + p * 128;
            const unsigned short* wl = Wl + (size_t)(wv * 16 + mrow) * 1536 + p * 128;
#pragma unroll
            for (int ks = 0; ks < 4; ks++) {
                int kk = ks * 32 + quad * 8;
                short8 ah[4], al[4];
#pragma unroll
                for (int t = 0; t < 4; t++) {
                    ah[t] = *(const short8*)&Xh[t * 16 + mrow][kk];
                    al[t] = *(const short8*)&Xl[t * 16 + mrow][kk];
                }
                short8 bh = *(const short8*)(wh + kk);
                short8 bl = *(const short8*)(wl + kk);
#pragma unroll
                for (int t = 0; t < 4; t++) {
                    acc[t] = __builtin_amdgcn_mfma_f32_16x16x32_bf16(ah[t], bh, acc[t], 0, 0, 0);
                    acc[t] = __builtin_amdgcn_mfma_f32_16x16x32_bf16(ah[t], bl, acc[t], 0, 0, 0);
                    acc[t] = __builtin_amdgcn_mfma_f32_16x16x32_bf16(al[t], bh, acc[t], 0, 0, 0);
                }
            }
        }
    }

    // epilogue: D layout col=lane&15, row=quad*4+reg
    int col = wv * 16 + mrow;
    float bv = (col < 28) ? bd[col] : bt[col - 28];
#pragma unroll
    for (int t = 0; t < 4; t++) {
#pragma unroll
        for (int rg = 0; rg < 4; rg++) {
            int r = base + t * 16 + quad * 4 + rg;
            if (r < N) {
                float v = acc[t][rg] + bv;
                v = v > 0.f ? v : 0.01f * v;
                out[(size_t)r * 128 + col] = v;
            }
        }
    }
}

// ================= Encoder small: cols 64..127 =================
__global__ __launch_bounds__(256) void enc_small_kernel(
    const float* __restrict__ nump, const float* __restrict__ catp,
    const float* __restrict__ nf,
    const float* __restrict__ Wn, const float* __restrict__ bn,
    const float* __restrict__ Wc, const float* __restrict__ bc,
    const float* __restrict__ Ww, const float* __restrict__ bw,
    float* __restrict__ out, int n)
{
    int node = blockIdx.x * 4 + (threadIdx.x >> 6);
    if (node >= n) return;
    int j = threadIdx.x & 63;
    float acc;
    if (j < 12) {
        acc = bn[j];
        for (int k = 0; k < 7; k++) acc += nump[(size_t)node * 7 + k] * Wn[k * 12 + j];
    } else if (j < 52) {
        int c = j - 12;
        acc = bc[c];
        for (int k = 0; k < 11; k++) acc += catp[(size_t)node * 11 + k] * Wc[k * 40 + c];
    } else {
        int c = j - 52;
        acc = bw[c] + nf[node] * Ww[c];
    }
    acc = acc > 0.f ? acc : 0.01f * acc;
    out[(size_t)node * 128 + 64 + j] = acc;
}

// ===== Weight prep: transpose + bf16-split. dst[m][col][k] = split(src[m][k][col]) =====
__global__ void prep_w_kernel(const float* __restrict__ src,
                              unsigned short* __restrict__ dh,
                              unsigned short* __restrict__ dl, int total)
{
    int idx = blockIdx.x * 256 + threadIdx.x;
    if (idx >= total) return;
    int m = idx >> 14, r = idx & 16383;
    int k = r >> 7, col = r & 127;
    unsigned short h, l;
    split_bf16(src[idx], h, l);
    int didx = (m << 14) | (col << 7) | k;
    dh[didx] = h; dl[didx] = l;
}

// ===== MFMA multi-phase dense: out = sum_p in_p @ W_p + b (fp32 via bf16 hi/lo 3-mult) =====
// 64 rows x 128 cols/block, 4 waves: wave w = rows 0..63 (4 tiles) x cols w*32..+31 (2 tiles).
// W pre-transposed [col][k] (B-frag order) read from global (L2). X staged fp32->split in LDS.
__global__ __launch_bounds__(256) void dense_mfma_kernel(
    const float* __restrict__ in0, const float* __restrict__ in1, const float* __restrict__ in2,
    int s0, int o0, int s1, int o1, int s2, int o2,
    const unsigned short* __restrict__ Wh, const unsigned short* __restrict__ Wl,
    int slot0, int slot1, int slot2,
    const float* __restrict__ bias, float* __restrict__ out,
    int nphases, int relu, int N)
{
    __shared__ unsigned short Xh[64][136];   // 17 KB (row stride 272B: 16B-aligned frags)
    __shared__ unsigned short Xl[64][136];   // 17 KB
    int base = blockIdx.x * 64;
    int lane = threadIdx.x & 63;
    int wv   = threadIdx.x >> 6;
    int srow = threadIdx.x >> 2;      // staging: row 0..63
    int sseg = threadIdx.x & 3;       // staging: 32-col segment
    int mrow = lane & 15;             // A row / B col / D col within tile
    int quad = lane >> 4;

    floatx4 acc[4][2];
#pragma unroll
    for (int t = 0; t < 4; t++)
#pragma unroll
        for (int ct = 0; ct < 2; ct++) acc[t][ct] = (floatx4){0.f, 0.f, 0.f, 0.f};

    for (int p = 0; p < nphases; p++) {
        const float* inp = (p == 0) ? in0 : (p == 1) ? in1 : in2;
        int st   = (p == 0) ? s0 : (p == 1) ? s1 : s2;
        int off  = (p == 0) ? o0 : (p == 1) ? o1 : o2;
        int slot = (p == 0) ? slot0 : (p == 1) ? slot1 : slot2;

        __syncthreads();   // prior phase's frag reads done before restaging
        {
            int gr = base + srow; if (gr >= N) gr = N - 1;
            const float* src = inp + (size_t)gr * st + off + sseg * 32;
            unsigned short th[32], tl[32];
#pragma unroll
            for (int q = 0; q < 8; q++) {
                float4 v = *(const float4*)(src + q * 4);
                split_bf16(v.x, th[q * 4 + 0], tl[q * 4 + 0]);
                split_bf16(v.y, th[q * 4 + 1], tl[q * 4 + 1]);
                split_bf16(v.z, th[q * 4 + 2], tl[q * 4 + 2]);
                split_bf16(v.w, th[q * 4 + 3], tl[q * 4 + 3]);
            }
#pragma unroll
            for (int q = 0; q < 4; q++) {
                *(short8*)&Xh[srow][sseg * 32 + q * 8] = *(short8*)&th[q * 8];
                *(short8*)&Xl[srow][sseg * 32 + q * 8] = *(short8*)&tl[q * 8];
            }
        }
        __syncthreads();

        const unsigned short* wh = Wh + (size_t)slot * 16384;
        const unsigned short* wl = Wl + (size_t)slot * 16384;
#pragma unroll
        for (int ks = 0; ks < 4; ks++) {
            int kk = ks * 32 + quad * 8;
            short8 ah[4], al[4];
#pragma unroll
            for (int t = 0; t < 4; t++) {
                ah[t] = *(const short8*)&Xh[t * 16 + mrow][kk];
                al[t] = *(const short8*)&Xl[t * 16 + mrow][kk];
            }
#pragma unroll
            for (int ct = 0; ct < 2; ct++) {
                int col = wv * 32 + ct * 16 + mrow;
                short8 bh = *(const short8*)(wh + col * 128 + kk);
                short8 bl = *(const short8*)(wl + col * 128 + kk);
#pragma unroll
                for (int t = 0; t < 4; t++) {
                    acc[t][ct] = __builtin_amdgcn_mfma_f32_16x16x32_bf16(ah[t], bh, acc[t][ct], 0, 0, 0);
                    acc[t][ct] = __builtin_amdgcn_mfma_f32_16x16x32_bf16(ah[t], bl, acc[t][ct], 0, 0, 0);
                    acc[t][ct] = __builtin_amdgcn_mfma_f32_16x16x32_bf16(al[t], bh, acc[t][ct], 0, 0, 0);
                }
            }
        }
    }

    // epilogue: D layout col=lane&15, row=quad*4+reg
#pragma unroll
    for (int ct = 0; ct < 2; ct++) {
        int col = wv * 32 + ct * 16 + mrow;
        float bv = bias[col];
#pragma unroll
        for (int t = 0; t < 4; t++) {
#pragma unroll
            for (int rg = 0; rg < 4; rg++) {
                int r = base + t * 16 + quad * 4 + rg;
                if (r < N) {
                    float v = acc[t][ct][rg] + bv;
                    if (relu) v = v > 0.f ? v : 0.01f * v;
                    out[(size_t)r * 128 + col] = v;
                }
            }
        }
    }
}

// ================= CSR build: count -> scan -> fill =================
__global__ void count_kernel(const int* __restrict__ ei, const int* __restrict__ et,
                             int* __restrict__ deg, int E, int N)
{
    int e = blockIdx.x * 256 + threadIdx.x;
    if (e < E) atomicAdd(&deg[(size_t)et[e] * N + ei[E + e]], 1);
}

__global__ void scan1_kernel(const int* __restrict__ deg, int* __restrict__ bsum, int m)
{
    int i = blockIdx.x * 256 + threadIdx.x;
    int v = (i < m) ? deg[i] : 0;
#pragma unroll
    for (int off = 32; off > 0; off >>= 1) v += __shfl_down(v, off);
    __shared__ int ws4[4];
    if ((threadIdx.x & 63) == 0) ws4[threadIdx.x >> 6] = v;
    __syncthreads();
    if (threadIdx.x == 0) bsum[blockIdx.x] = ws4[0] + ws4[1] + ws4[2] + ws4[3];
}

__global__ __launch_bounds__(1024) void scan2_kernel(int* __restrict__ bsum, int nb)
{
    __shared__ int s[1024];
    int t = threadIdx.x;
    int v = (t < nb) ? bsum[t] : 0;
    s[t] = v;
    __syncthreads();
    for (int off = 1; off < 1024; off <<= 1) {
        int u = 0;
        if (t >= off) u = s[t - off];
        __syncthreads();
        s[t] += u;
        __syncthreads();
    }
    if (t < nb) bsum[t] = s[t] - v;
}

__global__ void scan3_kernel(const int* __restrict__ deg, const int* __restrict__ bsum,
                             int* __restrict__ offs, int m)
{
    __shared__ int s[256];
    int i = blockIdx.x * 256 + threadIdx.x;
    int t = threadIdx.x;
    int v = (i < m) ? deg[i] : 0;
    s[t] = v;
    __syncthreads();
    for (int off = 1; off < 256; off <<= 1) {
        int u = 0;
        if (t >= off) u = s[t - off];
        __syncthreads();
        s[t] += u;
        __syncthreads();
    }
    if (i < m) offs[i] = bsum[blockIdx.x] + s[t] - v;
}

__global__ void fill_kernel(const int* __restrict__ ei, const int* __restrict__ et,
                            int* __restrict__ offs, int* __restrict__ ord, int E, int N)
{
    int e = blockIdx.x * 256 + threadIdx.x;
    if (e >= E) return;
    int b = et[e] * N + ei[E + e];
    int pos = atomicAdd(&offs[b], 1);
    ord[pos] = ei[e];
}

// ============ Combined 2-relation mean-gather ============
__global__ __launch_bounds__(256) void gather2_kernel(
    const float* __restrict__ x, const int* __restrict__ offs,
    const int* __restrict__ ord, float* __restrict__ G, int N)
{
    int d = blockIdx.x * 8 + (threadIdx.x >> 5);
    if (d >= N) return;
    int lane = threadIdx.x & 31;
#pragma unroll
    for (int r = 0; r < 2; r++) {
        int b = r * N + d;
        int end = offs[b];
        int beg = (b == 0) ? 0 : offs[b - 1];
        float4 acc = {0.f, 0.f, 0.f, 0.f};
        for (int p = beg; p < end; p++) {
            int s = ord[p];
            float4 v = *(const float4*)(x + (size_t)s * 128 + lane * 4);
            acc.x += v.x; acc.y += v.y; acc.z += v.z; acc.w += v.w;
        }
        int dg = end - beg;
        float invd = 1.0f / (float)(dg > 1 ? dg : 1);
        float4 o;
        o.x = acc.x * invd; o.y = acc.y * invd; o.z = acc.z * invd; o.w = acc.w * invd;
        *(float4*)(G + (size_t)d * 256 + r * 128 + lane * 4) = o;
    }
}

// ================= Head =================
__global__ __launch_bounds__(256) void head_kernel(
    const float* __restrict__ y, const float* __restrict__ W2,
    const float* __restrict__ b2, float* __restrict__ out, int n)
{
    int node = blockIdx.x * 4 + (threadIdx.x >> 6);
    if (node >= n) return;
    int lane = threadIdx.x & 63;
    float x0 = y[(size_t)node * 128 + lane];
    float x1 = y[(size_t)node * 128 + 64 + lane];
    float s0 = x0 * W2[lane * 2]     + x1 * W2[(lane + 64) * 2];
    float s1 = x0 * W2[lane * 2 + 1] + x1 * W2[(lane + 64) * 2 + 1];
#pragma unroll
    for (int off = 32; off > 0; off >>= 1) {
        s0 += __shfl_down(s0, off);
        s1 += __shfl_down(s1, off);
    }
    if (lane == 0) {
        out[(size_t)node * 2]     = s0 + b2[0];
        out[(size_t)node * 2 + 1] = s1 + b2[1];
    }
}

extern "C" void kernel_launch(void* const* d_in, const int* in_sizes, int n_in,
                              void* d_out, int out_size, void* d_ws, size_t ws_size,
                              hipStream_t stream)
{
    const float* des   = (const float*)d_in[0];
    const float* tweet = (const float*)d_in[1];
    const float* nump  = (const float*)d_in[2];
    const float* catp  = (const float*)d_in[3];
    const float* nf    = (const float*)d_in[4];
    const int*   ei    = (const int*)d_in[5];
    const int*   et    = (const int*)d_in[6];
    const float* Wd  = (const float*)d_in[7],  *bd  = (const float*)d_in[8];
    const float* Wt  = (const float*)d_in[9],  *bt  = (const float*)d_in[10];
    const float* Wn  = (const float*)d_in[11], *bn  = (const float*)d_in[12];
    const float* Wc  = (const float*)d_in[13], *bc  = (const float*)d_in[14];
    const float* Ww  = (const float*)d_in[15], *bw  = (const float*)d_in[16];
    const float* Win = (const float*)d_in[17], *bin = (const float*)d_in[18];
    const float* Wroot = (const float*)d_in[19];
    const float* Wrel  = (const float*)d_in[20];
    const float* brg   = (const float*)d_in[21];
    const float* Wo1 = (const float*)d_in[22], *bo1 = (const float*)d_in[23];
    const float* Wo2 = (const float*)d_in[24], *bo2 = (const float*)d_in[25];

    int N = in_sizes[0] / 768;   // 100000
    int E = in_sizes[6];         // 600000

    // ws: x[N*128] f32 | G[N*256] f32 | Wth/Wtl 14*16384 u16 | CSR ints. ~158.5 MB.
    float* x = (float*)d_ws;
    float* G = x + (size_t)N * 128;
    unsigned short* Wth = (unsigned short*)(G + (size_t)N * 256);
    unsigned short* Wtl = Wth + (size_t)14 * 16384;
    int* deg  = (int*)(Wtl + (size_t)14 * 16384);
    int* offs = deg + (size_t)2 * N;
    int* ord  = offs + (size_t)2 * N;
    int* bsum = ord + (size_t)E;

    // encoder weight (hi/lo split, 64x1536 u16 each = 384 KB) lives in the G region,
    // which is dead until the first gather2 — zero extra workspace.
    unsigned short* WEh = (unsigned short*)G;
    unsigned short* WEl = WEh + (size_t)64 * 1536;

    int m = 2 * N;
    int nb = (m + 255) / 256;         // 782 <= 1024
    int nblk = (N + 63) / 64;         // 1563

    hipMemsetAsync(deg, 0, (size_t)m * sizeof(int), stream);

    // weight prep: slots [0]=Win [1..4]=Wroot [5..12]=Wrel [13]=Wo1
    prep_w_kernel<<<(16384 + 255) / 256, 256, 0, stream>>>(Win, Wth, Wtl, 16384);
    prep_w_kernel<<<(4 * 16384 + 255) / 256, 256, 0, stream>>>(Wroot, Wth + 1 * 16384, Wtl + 1 * 16384, 4 * 16384);
    prep_w_kernel<<<(8 * 16384 + 255) / 256, 256, 0, stream>>>(Wrel, Wth + 5 * 16384, Wtl + 5 * 16384, 8 * 16384);
    prep_w_kernel<<<(16384 + 255) / 256, 256, 0, stream>>>(Wo1, Wth + 13 * 16384, Wtl + 13 * 16384, 16384);
    prep_wenc_kernel<<<dim3(64, 6), 256, 0, stream>>>(Wd, Wt, WEh, WEl);

    // encoder -> x
    enc_mfma_kernel<<<nblk, 256, 0, stream>>>(des, tweet, WEh, WEl, bd, bt, x, N);
    enc_small_kernel<<<(N + 3) / 4, 256, 0, stream>>>(
        nump, catp, nf, Wn, bn, Wc, bc, Ww, bw, x, N);

    // CSR build
    count_kernel<<<(E + 255) / 256, 256, 0, stream>>>(ei, et, deg, E, N);
    scan1_kernel<<<nb, 256, 0, stream>>>(deg, bsum, m);
    scan2_kernel<<<1, 1024, 0, stream>>>(bsum, nb);
    scan3_kernel<<<nb, 256, 0, stream>>>(deg, bsum, offs, m);
    fill_kernel<<<(E + 255) / 256, 256, 0, stream>>>(ei, et, offs, ord, E, N);

    // x = lrelu(x @ W_in + b_in)
    dense_mfma_kernel<<<nblk, 256, 0, stream>>>(
        x, x, x, 128, 0, 128, 0, 128, 0, Wth, Wtl, 0, 0, 0, bin, x, 1, 1, N);

    for (int i = 0; i < 4; i++) {
        gather2_kernel<<<(N + 7) / 8, 256, 0, stream>>>(x, offs, ord, G, N);
        // x = x@Wroot[i] + G0@Wrel[i][0] + G1@Wrel[i][1] + b
        dense_mfma_kernel<<<nblk, 256, 0, stream>>>(
            x, G, G, 128, 0, 256, 0, 256, 128,
            Wth, Wtl, 1 + i, 5 + 2 * i, 6 + 2 * i,
            brg + (size_t)i * 128, x, 3, 0, N);
    }

    // x = lrelu(x @ W_o1 + b_o1)
    dense_mfma_kernel<<<nblk, 256, 0, stream>>>(
        x, x, x, 128, 0, 128, 0, 128, 0, Wth, Wtl, 13, 13, 13, bo1, x, 1, 1, N);
    head_kernel<<<(N + 3) / 4, 256, 0, stream>>>(x, Wo2, bo2, (float*)d_out, N);
}